// Round 7
// baseline (566.962 us; speedup 1.0000x reference)
//
#include <hip/hip_runtime.h>

#define N_NODES  100000
#define NNZ_FEAT 2000000
#define N_EDGES  1600000
#define IN_DIM   256
#define OUT_DIM  64

__device__ __forceinline__ bool keep_entry(float u) {
    // exact replication of reference: floor(0.9f + u) >= 1.0f
    return floorf(0.9f + u) >= 1.0f;
}

// ---------------- CSR build (fused X + A, 4 entries/thread) ----------------

// Thread i < NNZ_FEAT/4 handles X entries [4i,4i+4); else A entries.
// int4/float4 loads keep full coalescing; the 4 atomic chains are independent.
__global__ void hist_fused(const int4* __restrict__ xr4, const float4* __restrict__ du4,
                           const int4* __restrict__ ar4,
                           int* __restrict__ cnt_x, int* __restrict__ cnt_a) {
    int i = blockIdx.x * blockDim.x + threadIdx.x;
    if (i < NNZ_FEAT / 4) {
        int4   r = xr4[i];
        float4 u = du4[i];
        if (keep_entry(u.x)) atomicAdd(&cnt_x[r.x], 1);
        if (keep_entry(u.y)) atomicAdd(&cnt_x[r.y], 1);
        if (keep_entry(u.z)) atomicAdd(&cnt_x[r.z], 1);
        if (keep_entry(u.w)) atomicAdd(&cnt_x[r.w], 1);
    } else if (i < (NNZ_FEAT + N_EDGES) / 4) {
        int4 r = ar4[i - NNZ_FEAT / 4];
        atomicAdd(&cnt_a[r.x], 1);
        atomicAdd(&cnt_a[r.y], 1);
        atomicAdd(&cnt_a[r.z], 1);
        atomicAdd(&cnt_a[r.w], 1);
    }
}

// 256 threads/block, 4 elems/thread -> 1024/block. blockIdx.y selects matrix.
__global__ void scan_pass1(const int* __restrict__ cntX, const int* __restrict__ cntA,
                           int* __restrict__ exX, int* __restrict__ exA,
                           int* __restrict__ bsX, int* __restrict__ bsA, int n) {
    const int* cnt = blockIdx.y ? cntA : cntX;
    int* excl = blockIdx.y ? exA : exX;
    int* bsum = blockIdx.y ? bsA : bsX;
    __shared__ int sh[256];
    int t = threadIdx.x;
    int base = blockIdx.x * 1024 + t * 4;
    int v0 = (base + 0 < n) ? cnt[base + 0] : 0;
    int v1 = (base + 1 < n) ? cnt[base + 1] : 0;
    int v2 = (base + 2 < n) ? cnt[base + 2] : 0;
    int v3 = (base + 3 < n) ? cnt[base + 3] : 0;
    int tsum = v0 + v1 + v2 + v3;
    sh[t] = tsum;
    __syncthreads();
    for (int off = 1; off < 256; off <<= 1) {
        int x = (t >= off) ? sh[t - off] : 0;
        __syncthreads();
        sh[t] += x;
        __syncthreads();
    }
    int texcl = sh[t] - tsum;
    if (base + 0 < n) excl[base + 0] = texcl;
    if (base + 1 < n) excl[base + 1] = texcl + v0;
    if (base + 2 < n) excl[base + 2] = texcl + v0 + v1;
    if (base + 3 < n) excl[base + 3] = texcl + v0 + v1 + v2;
    if (t == 255) bsum[blockIdx.x] = sh[255];
}

// grid (1,2), 128 threads; nb <= 128
__global__ void scan_pass2(const int* __restrict__ bsX, const int* __restrict__ bsA,
                           int* __restrict__ bsSX, int* __restrict__ bsSA,
                           int* __restrict__ totX, int* __restrict__ totA, int nb) {
    const int* bsum = blockIdx.y ? bsA : bsX;
    int* bsumS = blockIdx.y ? bsSA : bsSX;
    int* total = blockIdx.y ? totA : totX;
    __shared__ int sh[128];
    int t = threadIdx.x;
    sh[t] = (t < nb) ? bsum[t] : 0;
    __syncthreads();
    int orig = sh[t];
    for (int off = 1; off < 128; off <<= 1) {
        int x = (t >= off) ? sh[t - off] : 0;
        __syncthreads();
        sh[t] += x;
        __syncthreads();
    }
    if (t < nb) bsumS[t] = sh[t] - orig;
    if (t == 127) *total = sh[127];
}

__global__ void scan_pass3(int* __restrict__ stX, int* __restrict__ stA,
                           int* __restrict__ curX, int* __restrict__ curA,
                           const int* __restrict__ bsSX, const int* __restrict__ bsSA,
                           int n) {
    int* startArr = blockIdx.y ? stA : stX;
    int* cursor   = blockIdx.y ? curA : curX;
    const int* bS = blockIdx.y ? bsSA : bsSX;
    int i = blockIdx.x * blockDim.x + threadIdx.x;
    if (i < n) {
        int s = startArr[i] + bS[i >> 10];
        startArr[i] = s;
        cursor[i]   = s;
    }
}

// fused scatter, 4 entries/thread: X (dropout folded, dropped removed) then A,
// into row-sorted packed (val, col) pairs. 4 independent atomic->store chains.
__global__ void scatter_fused(const int4* __restrict__ xr4, const int4* __restrict__ xc4,
                              const float4* __restrict__ xv4, const float4* __restrict__ du4,
                              const int4* __restrict__ ar4, const int4* __restrict__ ac4,
                              const float4* __restrict__ av4,
                              int* __restrict__ curX, int* __restrict__ curA,
                              int2* __restrict__ pkX, int2* __restrict__ pkA) {
    const float SCL = (float)(1.0 / 0.9);
    int i = blockIdx.x * blockDim.x + threadIdx.x;
    if (i < NNZ_FEAT / 4) {
        int4   r = xr4[i];
        int4   c = xc4[i];
        float4 v = xv4[i];
        float4 u = du4[i];
        if (keep_entry(u.x)) { int p = atomicAdd(&curX[r.x], 1); pkX[p] = make_int2(__float_as_int(v.x * SCL), c.x); }
        if (keep_entry(u.y)) { int p = atomicAdd(&curX[r.y], 1); pkX[p] = make_int2(__float_as_int(v.y * SCL), c.y); }
        if (keep_entry(u.z)) { int p = atomicAdd(&curX[r.z], 1); pkX[p] = make_int2(__float_as_int(v.z * SCL), c.z); }
        if (keep_entry(u.w)) { int p = atomicAdd(&curX[r.w], 1); pkX[p] = make_int2(__float_as_int(v.w * SCL), c.w); }
    } else if (i < (NNZ_FEAT + N_EDGES) / 4) {
        int e = i - NNZ_FEAT / 4;
        int4   r = ar4[e];
        int4   c = ac4[e];
        float4 v = av4[e];
        { int p = atomicAdd(&curA[r.x], 1); pkA[p] = make_int2(__float_as_int(v.x), c.x); }
        { int p = atomicAdd(&curA[r.y], 1); pkA[p] = make_int2(__float_as_int(v.y), c.y); }
        { int p = atomicAdd(&curA[r.z], 1); pkA[p] = make_int2(__float_as_int(v.z), c.z); }
        { int p = atomicAdd(&curA[r.w], 1); pkA[p] = make_int2(__float_as_int(v.w), c.w); }
    }
}

// ---------------- gather SpMM (8/4/2/1 ILP ladder) ----------------

// one wave per row; lane = output dim. h[r,l] = sum_j v_j * W[c_j, l]
__global__ void __launch_bounds__(256) spmm1_csr(
        const int* __restrict__ startArr, const int2* __restrict__ pk,
        const float* __restrict__ W, float* __restrict__ h) {
    int wid  = (blockIdx.x * blockDim.x + threadIdx.x) >> 6;
    int lane = threadIdx.x & 63;
    if (wid >= N_NODES) return;
    int s = startArr[wid], e = startArr[wid + 1];
    float acc = 0.0f;
    int j = s;
    for (; j + 8 <= e; j += 8) {
        int2 p0 = pk[j + 0]; int2 p1 = pk[j + 1];
        int2 p2 = pk[j + 2]; int2 p3 = pk[j + 3];
        int2 p4 = pk[j + 4]; int2 p5 = pk[j + 5];
        int2 p6 = pk[j + 6]; int2 p7 = pk[j + 7];
        float g0 = W[p0.y * OUT_DIM + lane];
        float g1 = W[p1.y * OUT_DIM + lane];
        float g2 = W[p2.y * OUT_DIM + lane];
        float g3 = W[p3.y * OUT_DIM + lane];
        float g4 = W[p4.y * OUT_DIM + lane];
        float g5 = W[p5.y * OUT_DIM + lane];
        float g6 = W[p6.y * OUT_DIM + lane];
        float g7 = W[p7.y * OUT_DIM + lane];
        acc = fmaf(__int_as_float(p0.x), g0, acc);
        acc = fmaf(__int_as_float(p1.x), g1, acc);
        acc = fmaf(__int_as_float(p2.x), g2, acc);
        acc = fmaf(__int_as_float(p3.x), g3, acc);
        acc = fmaf(__int_as_float(p4.x), g4, acc);
        acc = fmaf(__int_as_float(p5.x), g5, acc);
        acc = fmaf(__int_as_float(p6.x), g6, acc);
        acc = fmaf(__int_as_float(p7.x), g7, acc);
    }
    if (j + 4 <= e) {
        int2 p0 = pk[j + 0]; int2 p1 = pk[j + 1];
        int2 p2 = pk[j + 2]; int2 p3 = pk[j + 3];
        float g0 = W[p0.y * OUT_DIM + lane];
        float g1 = W[p1.y * OUT_DIM + lane];
        float g2 = W[p2.y * OUT_DIM + lane];
        float g3 = W[p3.y * OUT_DIM + lane];
        acc = fmaf(__int_as_float(p0.x), g0, acc);
        acc = fmaf(__int_as_float(p1.x), g1, acc);
        acc = fmaf(__int_as_float(p2.x), g2, acc);
        acc = fmaf(__int_as_float(p3.x), g3, acc);
        j += 4;
    }
    if (j + 2 <= e) {
        int2 p0 = pk[j + 0]; int2 p1 = pk[j + 1];
        float g0 = W[p0.y * OUT_DIM + lane];
        float g1 = W[p1.y * OUT_DIM + lane];
        acc = fmaf(__int_as_float(p0.x), g0, acc);
        acc = fmaf(__int_as_float(p1.x), g1, acc);
        j += 2;
    }
    if (j < e) {
        int2 p = pk[j];
        acc = fmaf(__int_as_float(p.x), W[p.y * OUT_DIM + lane], acc);
    }
    h[wid * OUT_DIM + lane] = acc;
}

// one wave per row; out[r,l] = relu( sum_j a_j * h[c_j, l] )
__global__ void __launch_bounds__(256) spmm2_csr(
        const int* __restrict__ startArr, const int2* __restrict__ pk,
        const float* __restrict__ h, float* __restrict__ out) {
    int wid  = (blockIdx.x * blockDim.x + threadIdx.x) >> 6;
    int lane = threadIdx.x & 63;
    if (wid >= N_NODES) return;
    int s = startArr[wid], e = startArr[wid + 1];
    float acc = 0.0f;
    int j = s;
    for (; j + 8 <= e; j += 8) {
        int2 p0 = pk[j + 0]; int2 p1 = pk[j + 1];
        int2 p2 = pk[j + 2]; int2 p3 = pk[j + 3];
        int2 p4 = pk[j + 4]; int2 p5 = pk[j + 5];
        int2 p6 = pk[j + 6]; int2 p7 = pk[j + 7];
        float g0 = h[p0.y * OUT_DIM + lane];
        float g1 = h[p1.y * OUT_DIM + lane];
        float g2 = h[p2.y * OUT_DIM + lane];
        float g3 = h[p3.y * OUT_DIM + lane];
        float g4 = h[p4.y * OUT_DIM + lane];
        float g5 = h[p5.y * OUT_DIM + lane];
        float g6 = h[p6.y * OUT_DIM + lane];
        float g7 = h[p7.y * OUT_DIM + lane];
        acc = fmaf(__int_as_float(p0.x), g0, acc);
        acc = fmaf(__int_as_float(p1.x), g1, acc);
        acc = fmaf(__int_as_float(p2.x), g2, acc);
        acc = fmaf(__int_as_float(p3.x), g3, acc);
        acc = fmaf(__int_as_float(p4.x), g4, acc);
        acc = fmaf(__int_as_float(p5.x), g5, acc);
        acc = fmaf(__int_as_float(p6.x), g6, acc);
        acc = fmaf(__int_as_float(p7.x), g7, acc);
    }
    if (j + 4 <= e) {
        int2 p0 = pk[j + 0]; int2 p1 = pk[j + 1];
        int2 p2 = pk[j + 2]; int2 p3 = pk[j + 3];
        float g0 = h[p0.y * OUT_DIM + lane];
        float g1 = h[p1.y * OUT_DIM + lane];
        float g2 = h[p2.y * OUT_DIM + lane];
        float g3 = h[p3.y * OUT_DIM + lane];
        acc = fmaf(__int_as_float(p0.x), g0, acc);
        acc = fmaf(__int_as_float(p1.x), g1, acc);
        acc = fmaf(__int_as_float(p2.x), g2, acc);
        acc = fmaf(__int_as_float(p3.x), g3, acc);
        j += 4;
    }
    if (j + 2 <= e) {
        int2 p0 = pk[j + 0]; int2 p1 = pk[j + 1];
        float g0 = h[p0.y * OUT_DIM + lane];
        float g1 = h[p1.y * OUT_DIM + lane];
        acc = fmaf(__int_as_float(p0.x), g0, acc);
        acc = fmaf(__int_as_float(p1.x), g1, acc);
        j += 2;
    }
    if (j < e) {
        int2 p = pk[j];
        acc = fmaf(__int_as_float(p.x), h[p.y * OUT_DIM + lane], acc);
    }
    out[wid * OUT_DIM + lane] = fmaxf(acc, 0.0f);
}

// ---------------- launch ----------------

extern "C" void kernel_launch(void* const* d_in, const int* in_sizes, int n_in,
                              void* d_out, int out_size, void* d_ws, size_t ws_size,
                              hipStream_t stream) {
    const int*   x_rows       = (const int*)d_in[0];
    const int*   x_cols       = (const int*)d_in[1];
    const float* x_values     = (const float*)d_in[2];
    const int*   adj_rows     = (const int*)d_in[3];
    const int*   adj_cols     = (const int*)d_in[4];
    const float* adj_values   = (const float*)d_in[5];
    const float* drop_uniform = (const float*)d_in[6];
    const float* weights      = (const float*)d_in[7];
    float* out = (float*)d_out;

    // ---- workspace carve (256B-aligned) ----
    char* base = (char*)d_ws;
    size_t off = 0;
    auto carve = [&](size_t bytes) -> void* {
        void* p = base + off;
        off += (bytes + 255) & ~(size_t)255;
        return p;
    };
    float* h       = (float*)carve((size_t)N_NODES * OUT_DIM * sizeof(float)); // 25.6MB
    // one carve for BOTH histograms -> truly adjacent; single memset is safe
    int*   cnt_x   = (int*)carve(2 * N_NODES * sizeof(int));
    int*   cnt_a   = cnt_x + N_NODES;
    int*   start_x = (int*)carve((N_NODES + 1) * sizeof(int));
    int*   cur_x   = (int*)carve(N_NODES * sizeof(int));
    int*   start_a = (int*)carve((N_NODES + 1) * sizeof(int));
    int*   cur_a   = (int*)carve(N_NODES * sizeof(int));
    int*   bsum_x  = (int*)carve(128 * sizeof(int));
    int*   bsumS_x = (int*)carve(128 * sizeof(int));
    int*   bsum_a  = (int*)carve(128 * sizeof(int));
    int*   bsumS_a = (int*)carve(128 * sizeof(int));
    int2*  pk_x    = (int2*)carve((size_t)NNZ_FEAT * sizeof(int2)); // 16MB
    int2*  pk_a    = (int2*)carve((size_t)N_EDGES * sizeof(int2));  // 12.8MB
    (void)ws_size;

    const int NB = (N_NODES + 1023) / 1024;  // 98 scan blocks

    // zero both histograms in one shot (adjacent)
    hipMemsetAsync(cnt_x, 0, 2 * N_NODES * sizeof(int), stream);

    // fused histogram, 4 entries/thread
    {
        int threads = (NNZ_FEAT + N_EDGES) / 4;  // 900K
        hist_fused<<<(threads + 255) / 256, 256, 0, stream>>>(
            (const int4*)x_rows, (const float4*)drop_uniform, (const int4*)adj_rows,
            cnt_x, cnt_a);
    }

    // exclusive scans for both matrices (grid.y = 2)
    scan_pass1<<<dim3(NB, 2), 256, 0, stream>>>(
        cnt_x, cnt_a, start_x, start_a, bsum_x, bsum_a, N_NODES);
    scan_pass2<<<dim3(1, 2), 128, 0, stream>>>(
        bsum_x, bsum_a, bsumS_x, bsumS_a, start_x + N_NODES, start_a + N_NODES, NB);
    scan_pass3<<<dim3((N_NODES + 255) / 256, 2), 256, 0, stream>>>(
        start_x, start_a, cur_x, cur_a, bsumS_x, bsumS_a, N_NODES);

    // fused scatter, 4 entries/thread, into row-sorted packed copies
    {
        int threads = (NNZ_FEAT + N_EDGES) / 4;  // 900K
        scatter_fused<<<(threads + 255) / 256, 256, 0, stream>>>(
            (const int4*)x_rows, (const int4*)x_cols, (const float4*)x_values,
            (const float4*)drop_uniform,
            (const int4*)adj_rows, (const int4*)adj_cols, (const float4*)adj_values,
            cur_x, cur_a, pk_x, pk_a);
    }

    // gather SpMMs (no atomics, full-coverage stores, relu fused)
    {
        long long threads = (long long)N_NODES * OUT_DIM;  // 6.4M
        spmm1_csr<<<(unsigned)((threads + 255) / 256), 256, 0, stream>>>(
            start_x, pk_x, weights, h);
        spmm2_csr<<<(unsigned)((threads + 255) / 256), 256, 0, stream>>>(
            start_a, pk_a, h, out);
    }
}

// Round 9
// 439.436 us; speedup vs baseline: 1.2902x; 1.2902x over previous
//
#include <hip/hip_runtime.h>

#define N_NODES  100000
#define NNZ_FEAT 2000000
#define N_EDGES  1600000
#define IN_DIM   256
#define OUT_DIM  64

__device__ __forceinline__ bool keep_entry(float u) {
    // exact replication of reference: floor(0.9f + u) >= 1.0f
    return floorf(0.9f + u) >= 1.0f;
}

// ---------------- CSR build (fused X + A) ----------------

// Histogram AND per-entry within-row offset (the atomicAdd return).
// offs_* is written coalesced; dropped X entries leave their slot unwritten
// (never read back). This moves ALL atomics out of the scatter pass.
__global__ void hist_fused(const int* __restrict__ xr, const float* __restrict__ du,
                           const int* __restrict__ ar,
                           int* __restrict__ cnt_x, int* __restrict__ cnt_a,
                           int* __restrict__ offs_x, int* __restrict__ offs_a) {
    int i = blockIdx.x * blockDim.x + threadIdx.x;
    if (i < NNZ_FEAT) {
        if (keep_entry(du[i])) {
            offs_x[i] = atomicAdd(&cnt_x[xr[i]], 1);
        }
    } else {
        int e = i - NNZ_FEAT;
        if (e < N_EDGES) {
            offs_a[e] = atomicAdd(&cnt_a[ar[e]], 1);
        }
    }
}

// 256 threads/block, 4 elems/thread -> 1024/block. blockIdx.y selects matrix.
__global__ void scan_pass1(const int* __restrict__ cntX, const int* __restrict__ cntA,
                           int* __restrict__ exX, int* __restrict__ exA,
                           int* __restrict__ bsX, int* __restrict__ bsA, int n) {
    const int* cnt = blockIdx.y ? cntA : cntX;
    int* excl = blockIdx.y ? exA : exX;
    int* bsum = blockIdx.y ? bsA : bsX;
    __shared__ int sh[256];
    int t = threadIdx.x;
    int base = blockIdx.x * 1024 + t * 4;
    int v0 = (base + 0 < n) ? cnt[base + 0] : 0;
    int v1 = (base + 1 < n) ? cnt[base + 1] : 0;
    int v2 = (base + 2 < n) ? cnt[base + 2] : 0;
    int v3 = (base + 3 < n) ? cnt[base + 3] : 0;
    int tsum = v0 + v1 + v2 + v3;
    sh[t] = tsum;
    __syncthreads();
    for (int off = 1; off < 256; off <<= 1) {
        int x = (t >= off) ? sh[t - off] : 0;
        __syncthreads();
        sh[t] += x;
        __syncthreads();
    }
    int texcl = sh[t] - tsum;
    if (base + 0 < n) excl[base + 0] = texcl;
    if (base + 1 < n) excl[base + 1] = texcl + v0;
    if (base + 2 < n) excl[base + 2] = texcl + v0 + v1;
    if (base + 3 < n) excl[base + 3] = texcl + v0 + v1 + v2;
    if (t == 255) bsum[blockIdx.x] = sh[255];
}

// grid (1,2), 128 threads; nb <= 128
__global__ void scan_pass2(const int* __restrict__ bsX, const int* __restrict__ bsA,
                           int* __restrict__ bsSX, int* __restrict__ bsSA,
                           int* __restrict__ totX, int* __restrict__ totA, int nb) {
    const int* bsum = blockIdx.y ? bsA : bsX;
    int* bsumS = blockIdx.y ? bsSA : bsSX;
    int* total = blockIdx.y ? totA : totX;
    __shared__ int sh[128];
    int t = threadIdx.x;
    sh[t] = (t < nb) ? bsum[t] : 0;
    __syncthreads();
    int orig = sh[t];
    for (int off = 1; off < 128; off <<= 1) {
        int x = (t >= off) ? sh[t - off] : 0;
        __syncthreads();
        sh[t] += x;
        __syncthreads();
    }
    if (t < nb) bsumS[t] = sh[t] - orig;
    if (t == 127) *total = sh[127];
}

// finalize start arrays (no cursors needed anymore)
__global__ void scan_pass3(int* __restrict__ stX, int* __restrict__ stA,
                           const int* __restrict__ bsSX, const int* __restrict__ bsSA,
                           int n) {
    int* startArr = blockIdx.y ? stA : stX;
    const int* bS = blockIdx.y ? bsSA : bsSX;
    int i = blockIdx.x * blockDim.x + threadIdx.x;
    if (i < n) startArr[i] += bS[i >> 10];
}

// ATOMIC-FREE scatter: pos = start[row] + precomputed offset. Pure coalesced
// reads + one fire-and-forget scattered 8B store per entry.
__global__ void scatter_fused(const int* __restrict__ xr, const int* __restrict__ xc,
                              const float* __restrict__ xv, const float* __restrict__ du,
                              const int* __restrict__ ar, const int* __restrict__ ac,
                              const float* __restrict__ av,
                              const int* __restrict__ startX, const int* __restrict__ startA,
                              const int* __restrict__ offs_x, const int* __restrict__ offs_a,
                              int2* __restrict__ pkX, int2* __restrict__ pkA) {
    const float SCL = (float)(1.0 / 0.9);
    int i = blockIdx.x * blockDim.x + threadIdx.x;
    if (i < NNZ_FEAT) {
        if (!keep_entry(du[i])) return;
        int pos = startX[xr[i]] + offs_x[i];
        pkX[pos] = make_int2(__float_as_int(xv[i] * SCL), xc[i]);
    } else {
        int e = i - NNZ_FEAT;
        if (e < N_EDGES) {
            int pos = startA[ar[e]] + offs_a[e];
            pkA[pos] = make_int2(__float_as_int(av[e]), ac[e]);
        }
    }
}

// ---------------- gather SpMM (8/4/2/1 ILP ladder) ----------------

// one wave per row; lane = output dim. h[r,l] = sum_j v_j * W[c_j, l]
__global__ void __launch_bounds__(256) spmm1_csr(
        const int* __restrict__ startArr, const int2* __restrict__ pk,
        const float* __restrict__ W, float* __restrict__ h) {
    int wid  = (blockIdx.x * blockDim.x + threadIdx.x) >> 6;
    int lane = threadIdx.x & 63;
    if (wid >= N_NODES) return;
    int s = startArr[wid], e = startArr[wid + 1];
    float acc = 0.0f;
    int j = s;
    for (; j + 8 <= e; j += 8) {
        int2 p0 = pk[j + 0]; int2 p1 = pk[j + 1];
        int2 p2 = pk[j + 2]; int2 p3 = pk[j + 3];
        int2 p4 = pk[j + 4]; int2 p5 = pk[j + 5];
        int2 p6 = pk[j + 6]; int2 p7 = pk[j + 7];
        float g0 = W[p0.y * OUT_DIM + lane];
        float g1 = W[p1.y * OUT_DIM + lane];
        float g2 = W[p2.y * OUT_DIM + lane];
        float g3 = W[p3.y * OUT_DIM + lane];
        float g4 = W[p4.y * OUT_DIM + lane];
        float g5 = W[p5.y * OUT_DIM + lane];
        float g6 = W[p6.y * OUT_DIM + lane];
        float g7 = W[p7.y * OUT_DIM + lane];
        acc = fmaf(__int_as_float(p0.x), g0, acc);
        acc = fmaf(__int_as_float(p1.x), g1, acc);
        acc = fmaf(__int_as_float(p2.x), g2, acc);
        acc = fmaf(__int_as_float(p3.x), g3, acc);
        acc = fmaf(__int_as_float(p4.x), g4, acc);
        acc = fmaf(__int_as_float(p5.x), g5, acc);
        acc = fmaf(__int_as_float(p6.x), g6, acc);
        acc = fmaf(__int_as_float(p7.x), g7, acc);
    }
    if (j + 4 <= e) {
        int2 p0 = pk[j + 0]; int2 p1 = pk[j + 1];
        int2 p2 = pk[j + 2]; int2 p3 = pk[j + 3];
        float g0 = W[p0.y * OUT_DIM + lane];
        float g1 = W[p1.y * OUT_DIM + lane];
        float g2 = W[p2.y * OUT_DIM + lane];
        float g3 = W[p3.y * OUT_DIM + lane];
        acc = fmaf(__int_as_float(p0.x), g0, acc);
        acc = fmaf(__int_as_float(p1.x), g1, acc);
        acc = fmaf(__int_as_float(p2.x), g2, acc);
        acc = fmaf(__int_as_float(p3.x), g3, acc);
        j += 4;
    }
    if (j + 2 <= e) {
        int2 p0 = pk[j + 0]; int2 p1 = pk[j + 1];
        float g0 = W[p0.y * OUT_DIM + lane];
        float g1 = W[p1.y * OUT_DIM + lane];
        acc = fmaf(__int_as_float(p0.x), g0, acc);
        acc = fmaf(__int_as_float(p1.x), g1, acc);
        j += 2;
    }
    if (j < e) {
        int2 p = pk[j];
        acc = fmaf(__int_as_float(p.x), W[p.y * OUT_DIM + lane], acc);
    }
    h[wid * OUT_DIM + lane] = acc;
}

// one wave per row; out[r,l] = relu( sum_j a_j * h[c_j, l] )
__global__ void __launch_bounds__(256) spmm2_csr(
        const int* __restrict__ startArr, const int2* __restrict__ pk,
        const float* __restrict__ h, float* __restrict__ out) {
    int wid  = (blockIdx.x * blockDim.x + threadIdx.x) >> 6;
    int lane = threadIdx.x & 63;
    if (wid >= N_NODES) return;
    int s = startArr[wid], e = startArr[wid + 1];
    float acc = 0.0f;
    int j = s;
    for (; j + 8 <= e; j += 8) {
        int2 p0 = pk[j + 0]; int2 p1 = pk[j + 1];
        int2 p2 = pk[j + 2]; int2 p3 = pk[j + 3];
        int2 p4 = pk[j + 4]; int2 p5 = pk[j + 5];
        int2 p6 = pk[j + 6]; int2 p7 = pk[j + 7];
        float g0 = h[p0.y * OUT_DIM + lane];
        float g1 = h[p1.y * OUT_DIM + lane];
        float g2 = h[p2.y * OUT_DIM + lane];
        float g3 = h[p3.y * OUT_DIM + lane];
        float g4 = h[p4.y * OUT_DIM + lane];
        float g5 = h[p5.y * OUT_DIM + lane];
        float g6 = h[p6.y * OUT_DIM + lane];
        float g7 = h[p7.y * OUT_DIM + lane];
        acc = fmaf(__int_as_float(p0.x), g0, acc);
        acc = fmaf(__int_as_float(p1.x), g1, acc);
        acc = fmaf(__int_as_float(p2.x), g2, acc);
        acc = fmaf(__int_as_float(p3.x), g3, acc);
        acc = fmaf(__int_as_float(p4.x), g4, acc);
        acc = fmaf(__int_as_float(p5.x), g5, acc);
        acc = fmaf(__int_as_float(p6.x), g6, acc);
        acc = fmaf(__int_as_float(p7.x), g7, acc);
    }
    if (j + 4 <= e) {
        int2 p0 = pk[j + 0]; int2 p1 = pk[j + 1];
        int2 p2 = pk[j + 2]; int2 p3 = pk[j + 3];
        float g0 = h[p0.y * OUT_DIM + lane];
        float g1 = h[p1.y * OUT_DIM + lane];
        float g2 = h[p2.y * OUT_DIM + lane];
        float g3 = h[p3.y * OUT_DIM + lane];
        acc = fmaf(__int_as_float(p0.x), g0, acc);
        acc = fmaf(__int_as_float(p1.x), g1, acc);
        acc = fmaf(__int_as_float(p2.x), g2, acc);
        acc = fmaf(__int_as_float(p3.x), g3, acc);
        j += 4;
    }
    if (j + 2 <= e) {
        int2 p0 = pk[j + 0]; int2 p1 = pk[j + 1];
        float g0 = h[p0.y * OUT_DIM + lane];
        float g1 = h[p1.y * OUT_DIM + lane];
        acc = fmaf(__int_as_float(p0.x), g0, acc);
        acc = fmaf(__int_as_float(p1.x), g1, acc);
        j += 2;
    }
    if (j < e) {
        int2 p = pk[j];
        acc = fmaf(__int_as_float(p.x), h[p.y * OUT_DIM + lane], acc);
    }
    out[wid * OUT_DIM + lane] = fmaxf(acc, 0.0f);
}

// ---------------- launch ----------------

extern "C" void kernel_launch(void* const* d_in, const int* in_sizes, int n_in,
                              void* d_out, int out_size, void* d_ws, size_t ws_size,
                              hipStream_t stream) {
    const int*   x_rows       = (const int*)d_in[0];
    const int*   x_cols       = (const int*)d_in[1];
    const float* x_values     = (const float*)d_in[2];
    const int*   adj_rows     = (const int*)d_in[3];
    const int*   adj_cols     = (const int*)d_in[4];
    const float* adj_values   = (const float*)d_in[5];
    const float* drop_uniform = (const float*)d_in[6];
    const float* weights      = (const float*)d_in[7];
    float* out = (float*)d_out;

    // ---- workspace carve (256B-aligned) ----
    char* base = (char*)d_ws;
    size_t off = 0;
    auto carve = [&](size_t bytes) -> void* {
        void* p = base + off;
        off += (bytes + 255) & ~(size_t)255;
        return p;
    };
    float* h       = (float*)carve((size_t)N_NODES * OUT_DIM * sizeof(float)); // 25.6MB
    // one carve for BOTH histograms -> truly adjacent; single memset is safe
    int*   cnt_x   = (int*)carve(2 * N_NODES * sizeof(int));
    int*   cnt_a   = cnt_x + N_NODES;
    int*   start_x = (int*)carve((N_NODES + 1) * sizeof(int));
    int*   start_a = (int*)carve((N_NODES + 1) * sizeof(int));
    int*   bsum_x  = (int*)carve(128 * sizeof(int));
    int*   bsumS_x = (int*)carve(128 * sizeof(int));
    int*   bsum_a  = (int*)carve(128 * sizeof(int));
    int*   bsumS_a = (int*)carve(128 * sizeof(int));
    int*   offs_x  = (int*)carve((size_t)NNZ_FEAT * sizeof(int));   // 8MB
    int*   offs_a  = (int*)carve((size_t)N_EDGES * sizeof(int));    // 6.4MB
    int2*  pk_x    = (int2*)carve((size_t)NNZ_FEAT * sizeof(int2)); // 16MB
    int2*  pk_a    = (int2*)carve((size_t)N_EDGES * sizeof(int2));  // 12.8MB
    (void)ws_size;

    const int NB = (N_NODES + 1023) / 1024;  // 98 scan blocks

    // zero both histograms in one shot (adjacent)
    hipMemsetAsync(cnt_x, 0, 2 * N_NODES * sizeof(int), stream);

    // fused histogram + per-entry offset capture (all atomics live here)
    {
        int total = NNZ_FEAT + N_EDGES;
        hist_fused<<<(total + 255) / 256, 256, 0, stream>>>(
            x_rows, drop_uniform, adj_rows, cnt_x, cnt_a, offs_x, offs_a);
    }

    // exclusive scans for both matrices (grid.y = 2); cnt -> start
    scan_pass1<<<dim3(NB, 2), 256, 0, stream>>>(
        cnt_x, cnt_a, start_x, start_a, bsum_x, bsum_a, N_NODES);
    scan_pass2<<<dim3(1, 2), 128, 0, stream>>>(
        bsum_x, bsum_a, bsumS_x, bsumS_a, start_x + N_NODES, start_a + N_NODES, NB);
    scan_pass3<<<dim3((N_NODES + 255) / 256, 2), 256, 0, stream>>>(
        start_x, start_a, bsumS_x, bsumS_a, N_NODES);

    // atomic-free scatter into row-sorted packed copies
    {
        int total = NNZ_FEAT + N_EDGES;
        scatter_fused<<<(total + 255) / 256, 256, 0, stream>>>(
            x_rows, x_cols, x_values, drop_uniform, adj_rows, adj_cols, adj_values,
            start_x, start_a, offs_x, offs_a, pk_x, pk_a);
    }

    // gather SpMMs (no atomics, full-coverage stores, relu fused)
    {
        long long threads = (long long)N_NODES * OUT_DIM;  // 6.4M
        spmm1_csr<<<(unsigned)((threads + 255) / 256), 256, 0, stream>>>(
            start_x, pk_x, weights, h);
        spmm2_csr<<<(unsigned)((threads + 255) / 256), 256, 0, stream>>>(
            start_a, pk_a, h, out);
    }
}